// Round 6
// baseline (336.396 us; speedup 1.0000x reference)
//
#include <hip/hip_runtime.h>

#define Bd 16
#define Cd 512
#define Hd 64
#define Wd 64
#define HWd (Hd * Wd)
#define NCLS 5
#define BETA 2.0f
#define EPS2 (0.001f * 0.001f)

// native 4-float vector: __builtin_nontemporal_load requires a scalar/native
// vector pointee (HIP's float4 is a struct and is rejected).
typedef float f4 __attribute__((ext_vector_type(4)));

// Contiguous-stream layout: each block owns ONE linear 64 KB span per tensor
// (4 channels x full HW), matching the access shape of the 6.9 TB/s
// fillBuffer observed in-profile. Previous layout had 16 strided 4 KB
// sub-streams per block x 4096 blocks (~65K DRAM streams) -> page thrash.
constexpr int CH = 4;
constexpr int NCCHUNK = Cd / CH;               // 128
constexpr int F4_PER_BLOCK = CH * HWd / 4;     // 4096 f4 (64 KB) per tensor
constexpr int NIT = F4_PER_BLOCK / 256;        // 16 iterations of 256 threads

// grid = (NCCHUNK, Bd) = (128,16) = 2048 blocks -> exactly 8/CU, no tail.
__global__ __launch_bounds__(256, 8) void seg_partial_kernel(
    const float* __restrict__ rec, const float* __restrict__ aln,
    const int* __restrict__ mask,
    float* __restrict__ segsum, float* __restrict__ segcnt)
{
    __shared__ float binS[NCLS];
    __shared__ float binC[NCLS];
    const int t = threadIdx.x;
    if (t < NCLS) { binS[t] = 0.0f; binC[t] = 0.0f; }
    __syncthreads();

    const int cz = blockIdx.x;    // channel chunk
    const int b  = blockIdx.y;

    const size_t base4 = ((size_t)(b * Cd + cz * CH) * HWd) / 4;
    const f4* __restrict__ rv = (const f4*)rec + base4;
    const f4* __restrict__ av = (const f4*)aln + base4;
    const int4* __restrict__ mv = (const int4*)(mask + b * HWd);

    // one 16 KB mask slice serves all 4 channels: 4 int4/thread, loaded once
    // (normal load: reused by the 128 blocks of this b -> keep cacheable).
    int4 M[4];
#pragma unroll
    for (int j = 0; j < 4; ++j) M[j] = mv[j * 256 + t];

    // per-class register accumulators (compile-time indexed after unroll)
    float acc[NCLS] = {0.f, 0.f, 0.f, 0.f, 0.f};
    float cnt[NCLS] = {0.f, 0.f, 0.f, 0.f, 0.f};

    // linear sweep: f4 index g = it*256 + t walks the 64 KB span
    // contiguously. hw position of g repeats with period 1024 f4 -> mask
    // reg M[it&3]. 4 nt loads (2 KB/lane-pair) in flight per 2-it batch.
#pragma unroll
    for (int it = 0; it < NIT; it += 2) {
        const int g0 = it * 256 + t;
        const int g1 = (it + 1) * 256 + t;
        f4 R0 = __builtin_nontemporal_load(rv + g0);
        f4 A0 = __builtin_nontemporal_load(av + g0);
        f4 R1 = __builtin_nontemporal_load(rv + g1);
        f4 A1 = __builtin_nontemporal_load(av + g1);
        const int4 m0 = M[it & 3];
        const int4 m1 = M[(it + 1) & 3];

        float d0x = R0.x - A0.x; d0x *= d0x;
        float d0y = R0.y - A0.y; d0y *= d0y;
        float d0z = R0.z - A0.z; d0z *= d0z;
        float d0w = R0.w - A0.w; d0w *= d0w;
        float d1x = R1.x - A1.x; d1x *= d1x;
        float d1y = R1.y - A1.y; d1y *= d1y;
        float d1z = R1.z - A1.z; d1z *= d1z;
        float d1w = R1.w - A1.w; d1w *= d1w;

#pragma unroll
        for (int c = 0; c < NCLS; ++c) {
            acc[c] += ((m0.x == c) ? d0x : 0.f) + ((m0.y == c) ? d0y : 0.f)
                    + ((m0.z == c) ? d0z : 0.f) + ((m0.w == c) ? d0w : 0.f)
                    + ((m1.x == c) ? d1x : 0.f) + ((m1.y == c) ? d1y : 0.f)
                    + ((m1.z == c) ? d1z : 0.f) + ((m1.w == c) ? d1w : 0.f);
        }
    }

    // counts: mask-only, each pixel exactly once -> cz==0 blocks only
    if (cz == 0) {
#pragma unroll
        for (int j = 0; j < 4; ++j) {
#pragma unroll
            for (int c = 0; c < NCLS; ++c) {
                cnt[c] += (float)((M[j].x == c) + (M[j].y == c)
                                + (M[j].z == c) + (M[j].w == c));
            }
        }
    }

    // wave butterfly reduce (no LDS traffic in/near the hot loop)
#pragma unroll
    for (int c = 0; c < NCLS; ++c) {
#pragma unroll
        for (int off = 32; off > 0; off >>= 1)
            acc[c] += __shfl_xor(acc[c], off);
    }
    if (cz == 0) {
#pragma unroll
        for (int c = 0; c < NCLS; ++c) {
#pragma unroll
            for (int off = 32; off > 0; off >>= 1)
                cnt[c] += __shfl_xor(cnt[c], off);
        }
    }

    const int lane = t & 63;
    if (lane == 0) {
        const float scale = 1.0f / (float)Cd;   // channel mean
#pragma unroll
        for (int c = 0; c < NCLS; ++c) {
            atomicAdd(&binS[c], acc[c] * scale);
            if (cz == 0) atomicAdd(&binC[c], cnt[c]);
        }
    }
    __syncthreads();
    // one global atomic per (block,class) into the 80 final bins
    if (t < NCLS) {
        atomicAdd(&segsum[b * NCLS + t], binS[t]);
        if (cz == 0) atomicAdd(&segcnt[b * NCLS + t], binC[t]);
    }
}

// Kernel 2: 80 segments -> scalar. One block of 128 threads.
__global__ __launch_bounds__(128) void finalize_kernel(
    const float* __restrict__ segsum, const float* __restrict__ segcnt,
    float* __restrict__ out)
{
    __shared__ float sMax[128];
    __shared__ float sSum[128];
    const int t = threadIdx.x;

    float s = 0.0f, cnt = 0.0f;
    if (t < Bd * NCLS) { s = segsum[t]; cnt = segcnt[t]; }
    const float avg = s / fmaxf(cnt, 1.0f);   // empty segments -> 0

    sMax[t] = avg;
    __syncthreads();
#pragma unroll
    for (int off = 64; off > 0; off >>= 1) {
        if (t < off) sMax[t] = fmaxf(sMax[t], sMax[t + off]);
        __syncthreads();
    }
    const float wmax = sMax[0];

    float w = (wmax > 0.0f) ? (avg / (wmax + EPS2)) : (avg + EPS2);
    w = fminf(fmaxf(w, 0.0f), 1.0f);

    sSum[t] = s * (w * BETA + 1.0f);
    __syncthreads();
#pragma unroll
    for (int off = 64; off > 0; off >>= 1) {
        if (t < off) sSum[t] += sSum[t + off];
        __syncthreads();
    }
    if (t == 0) out[0] = sSum[0] / (float)(Bd * HWd);
}

extern "C" void kernel_launch(void* const* d_in, const int* in_sizes, int n_in,
                              void* d_out, int out_size, void* d_ws, size_t ws_size,
                              hipStream_t stream) {
    const float* rec  = (const float*)d_in[0];
    const float* aln  = (const float*)d_in[1];
    const int*   mask = (const int*)d_in[2];
    float* out = (float*)d_out;

    float* segsum = (float*)d_ws;
    float* segcnt = segsum + Bd * NCLS;

    // zero the 2*80 accumulators (ws is re-poisoned to 0xAA before every launch)
    (void)hipMemsetAsync(d_ws, 0, 2 * Bd * NCLS * sizeof(float), stream);

    dim3 grid(NCCHUNK, Bd);   // (128, 16) = 2048 blocks, 8/CU, no tail
    seg_partial_kernel<<<grid, 256, 0, stream>>>(rec, aln, mask, segsum, segcnt);
    finalize_kernel<<<1, 128, 0, stream>>>(segsum, segcnt, out);
}

// Round 7
// 301.424 us; speedup vs baseline: 1.1160x; 1.1160x over previous
//
#include <hip/hip_runtime.h>

#define Bd 16
#define Cd 512
#define Hd 64
#define Wd 64
#define HWd (Hd * Wd)
#define NCLS 5
#define BETA 2.0f
#define EPS2 (0.001f * 0.001f)

// native 4-float vector: __builtin_nontemporal_load requires a scalar/native
// vector pointee (HIP's float4 is a struct and is rejected).
typedef float f4 __attribute__((ext_vector_type(4)));

// Contiguous-stream layout: each block owns ONE linear 64 KB span per tensor
// (4 channels x full HW), the same access shape as the in-profile 6.9 TB/s
// fillBuffer. Key trick: thread t revisits pixel-group (it&3)*256+t every 4
// iterations (channel period 1024 f4), so channel-sums accumulate into 4
// NAMED f4 registers -- the hot loop is pure sub+fma, no mask, no
// predication, no LDS. Mask binning happens once, in the epilogue.
constexpr int CH = 4;
constexpr int NCCHUNK = Cd / CH;               // 128
constexpr int F4_PER_BLOCK = CH * HWd / 4;     // 4096 f4 (64 KB) per tensor
constexpr int NIT = F4_PER_BLOCK / 256;        // 16 iterations of 256 threads

// (256,4): VGPR cap 128. (256,8) twice produced VGPR=32 + massive scratch
// spill (round 6: WRITE_SIZE 233 MB). Occupancy is irrelevant for linear
// streams (fill hits 6.9 TB/s at 9.3% occupancy).
// grid = (NCCHUNK, Bd) = (128,16) = 2048 blocks.
__global__ __launch_bounds__(256, 4) void seg_partial_kernel(
    const float* __restrict__ rec, const float* __restrict__ aln,
    const int* __restrict__ mask,
    float* __restrict__ segsum, float* __restrict__ segcnt)
{
    __shared__ float binS[NCLS];
    __shared__ float binC[NCLS];
    const int t = threadIdx.x;
    if (t < NCLS) { binS[t] = 0.0f; binC[t] = 0.0f; }
    __syncthreads();

    const int cz = blockIdx.x;    // channel chunk
    const int b  = blockIdx.y;

    const size_t base4 = ((size_t)(b * Cd + cz * CH) * HWd) / 4;
    const f4* __restrict__ rv = (const f4*)rec + base4;
    const f4* __restrict__ av = (const f4*)aln + base4;

    f4 acc0 = {0.f, 0.f, 0.f, 0.f};
    f4 acc1 = {0.f, 0.f, 0.f, 0.f};
    f4 acc2 = {0.f, 0.f, 0.f, 0.f};
    f4 acc3 = {0.f, 0.f, 0.f, 0.f};

    // 4 batches of 4 f4-pairs: 8 nt dwordx4 loads (32 data VGPRs) in flight
    // before any use. Pure streaming: 16 VALU per 128 B loaded.
#pragma unroll
    for (int it = 0; it < NIT; it += 4) {
        const int g = it * 256 + t;
        f4 R0 = __builtin_nontemporal_load(rv + g);
        f4 A0 = __builtin_nontemporal_load(av + g);
        f4 R1 = __builtin_nontemporal_load(rv + g + 256);
        f4 A1 = __builtin_nontemporal_load(av + g + 256);
        f4 R2 = __builtin_nontemporal_load(rv + g + 512);
        f4 A2 = __builtin_nontemporal_load(av + g + 512);
        f4 R3 = __builtin_nontemporal_load(rv + g + 768);
        f4 A3 = __builtin_nontemporal_load(av + g + 768);
        f4 d;
        d = R0 - A0; acc0 += d * d;   // ext_vector elementwise fma
        d = R1 - A1; acc1 += d * d;
        d = R2 - A2; acc2 += d * d;
        d = R3 - A3; acc3 += d * d;
    }

    // epilogue: load the 4 mask int4s (cacheable -- shared by the 128 blocks
    // of this b) and bin 16 pixel-sums via LDS atomics (proven round-0-3).
    const int4* __restrict__ mv = (const int4*)(mask + b * HWd);
    const int4 m0 = mv[0 * 256 + t];
    const int4 m1 = mv[1 * 256 + t];
    const int4 m2 = mv[2 * 256 + t];
    const int4 m3 = mv[3 * 256 + t];

    const float scale = 1.0f / (float)Cd;   // channel mean
    atomicAdd(&binS[m0.x], acc0.x * scale);
    atomicAdd(&binS[m0.y], acc0.y * scale);
    atomicAdd(&binS[m0.z], acc0.z * scale);
    atomicAdd(&binS[m0.w], acc0.w * scale);
    atomicAdd(&binS[m1.x], acc1.x * scale);
    atomicAdd(&binS[m1.y], acc1.y * scale);
    atomicAdd(&binS[m1.z], acc1.z * scale);
    atomicAdd(&binS[m1.w], acc1.w * scale);
    atomicAdd(&binS[m2.x], acc2.x * scale);
    atomicAdd(&binS[m2.y], acc2.y * scale);
    atomicAdd(&binS[m2.z], acc2.z * scale);
    atomicAdd(&binS[m2.w], acc2.w * scale);
    atomicAdd(&binS[m3.x], acc3.x * scale);
    atomicAdd(&binS[m3.y], acc3.y * scale);
    atomicAdd(&binS[m3.z], acc3.z * scale);
    atomicAdd(&binS[m3.w], acc3.w * scale);
    if (cz == 0) {   // counts: each pixel exactly once, by chunk-0 blocks
        atomicAdd(&binC[m0.x], 1.0f);
        atomicAdd(&binC[m0.y], 1.0f);
        atomicAdd(&binC[m0.z], 1.0f);
        atomicAdd(&binC[m0.w], 1.0f);
        atomicAdd(&binC[m1.x], 1.0f);
        atomicAdd(&binC[m1.y], 1.0f);
        atomicAdd(&binC[m1.z], 1.0f);
        atomicAdd(&binC[m1.w], 1.0f);
        atomicAdd(&binC[m2.x], 1.0f);
        atomicAdd(&binC[m2.y], 1.0f);
        atomicAdd(&binC[m2.z], 1.0f);
        atomicAdd(&binC[m2.w], 1.0f);
        atomicAdd(&binC[m3.x], 1.0f);
        atomicAdd(&binC[m3.y], 1.0f);
        atomicAdd(&binC[m3.z], 1.0f);
        atomicAdd(&binC[m3.w], 1.0f);
    }
    __syncthreads();
    // one global atomic per (block,class) into the 80 final bins
    if (t < NCLS) {
        atomicAdd(&segsum[b * NCLS + t], binS[t]);
        if (cz == 0) atomicAdd(&segcnt[b * NCLS + t], binC[t]);
    }
}

// Kernel 2: 80 segments -> scalar. One block of 128 threads.
__global__ __launch_bounds__(128) void finalize_kernel(
    const float* __restrict__ segsum, const float* __restrict__ segcnt,
    float* __restrict__ out)
{
    __shared__ float sMax[128];
    __shared__ float sSum[128];
    const int t = threadIdx.x;

    float s = 0.0f, cnt = 0.0f;
    if (t < Bd * NCLS) { s = segsum[t]; cnt = segcnt[t]; }
    const float avg = s / fmaxf(cnt, 1.0f);   // empty segments -> 0

    sMax[t] = avg;
    __syncthreads();
#pragma unroll
    for (int off = 64; off > 0; off >>= 1) {
        if (t < off) sMax[t] = fmaxf(sMax[t], sMax[t + off]);
        __syncthreads();
    }
    const float wmax = sMax[0];

    float w = (wmax > 0.0f) ? (avg / (wmax + EPS2)) : (avg + EPS2);
    w = fminf(fmaxf(w, 0.0f), 1.0f);

    sSum[t] = s * (w * BETA + 1.0f);
    __syncthreads();
#pragma unroll
    for (int off = 64; off > 0; off >>= 1) {
        if (t < off) sSum[t] += sSum[t + off];
        __syncthreads();
    }
    if (t == 0) out[0] = sSum[0] / (float)(Bd * HWd);
}

extern "C" void kernel_launch(void* const* d_in, const int* in_sizes, int n_in,
                              void* d_out, int out_size, void* d_ws, size_t ws_size,
                              hipStream_t stream) {
    const float* rec  = (const float*)d_in[0];
    const float* aln  = (const float*)d_in[1];
    const int*   mask = (const int*)d_in[2];
    float* out = (float*)d_out;

    float* segsum = (float*)d_ws;
    float* segcnt = segsum + Bd * NCLS;

    // zero the 2*80 accumulators (ws is re-poisoned to 0xAA before every launch)
    (void)hipMemsetAsync(d_ws, 0, 2 * Bd * NCLS * sizeof(float), stream);

    dim3 grid(NCCHUNK, Bd);   // (128, 16) = 2048 blocks
    seg_partial_kernel<<<grid, 256, 0, stream>>>(rec, aln, mask, segsum, segcnt);
    finalize_kernel<<<1, 128, 0, stream>>>(segsum, segcnt, out);
}

// Round 8
// 266.643 us; speedup vs baseline: 1.2616x; 1.1304x over previous
//
#include <hip/hip_runtime.h>

#define Bd 16
#define Cd 512
#define Hd 64
#define Wd 64
#define HWd (Hd * Wd)
#define NCLS 5
#define BETA 2.0f
#define EPS2 (0.001f * 0.001f)

// native 4-float vector: __builtin_nontemporal_load requires a scalar/native
// vector pointee (HIP's float4 is a struct and is rejected).
typedef float f4 __attribute__((ext_vector_type(4)));

// Round-5 structure (best measured: seg_partial < 77 us, dur 268 us):
// CH=8 -> grid (4,16,64) = 4096 blocks; each thread owns ONE pixel-quad and
// sweeps its 8 channels (two 4-channel batches of 8 nt dwordx4 loads).
// New this round: __builtin_amdgcn_sched_barrier(0) between each load batch
// and its math. R3/R7 showed the compiler otherwise sinks loads to their
// uses (VGPR=36 = only ~2 loads in flight); the fence forces all 8
// outstanding. (256,6): VGPR cap ~84 so the fenced batch (32 data regs +
// addresses) fits WITHOUT spilling ((256,8)'s 64-cap risked a round-6-style
// spill; spill traffic measured 2x worse than any scheduling gain).
constexpr int CH = 8;
constexpr int NCCHUNK = Cd / CH;      // 64
constexpr int PIX_PER_BLOCK = 1024;   // 256 threads * 4 pixels (f4)

// Kernel 1: per-pixel channel-MSE partial sums -> per-(batch,class) segment
// sums via LDS bins + one global atomic per (block,class).
// grid = (HW/1024, B, NCCHUNK), block = 256
__global__ __launch_bounds__(256, 6) void seg_partial_kernel(
    const float* __restrict__ rec, const float* __restrict__ aln,
    const int* __restrict__ mask,
    float* __restrict__ segsum, float* __restrict__ segcnt)
{
    __shared__ float binS[NCLS];
    __shared__ float binC[NCLS];
    const int tid = threadIdx.x;
    if (tid < NCLS) { binS[tid] = 0.0f; binC[tid] = 0.0f; }
    __syncthreads();

    const int b   = blockIdx.y;
    const int hw0 = blockIdx.x * PIX_PER_BLOCK + tid * 4;
    const int c0  = blockIdx.z * CH;

    const size_t base = (size_t)(b * Cd + c0) * HWd + hw0;
    const f4* __restrict__ rv = (const f4*)(rec + base);
    const f4* __restrict__ av = (const f4*)(aln + base);
    constexpr int CSTRIDE = HWd / 4;   // f4 stride between channels

    // independent mask load (cacheable: shared by the 64 c-chunks of this b)
    const int4 m = *(const int4*)(mask + b * HWd + hw0);

    f4 acc = {0.f, 0.f, 0.f, 0.f};   // per-pixel sum over channels

#pragma unroll
    for (int batch = 0; batch < 2; ++batch) {
        const f4* r4 = rv + (size_t)(batch * 4) * CSTRIDE;
        const f4* a4 = av + (size_t)(batch * 4) * CSTRIDE;
        f4 R0 = __builtin_nontemporal_load(r4 + 0 * CSTRIDE);
        f4 A0 = __builtin_nontemporal_load(a4 + 0 * CSTRIDE);
        f4 R1 = __builtin_nontemporal_load(r4 + 1 * CSTRIDE);
        f4 A1 = __builtin_nontemporal_load(a4 + 1 * CSTRIDE);
        f4 R2 = __builtin_nontemporal_load(r4 + 2 * CSTRIDE);
        f4 A2 = __builtin_nontemporal_load(a4 + 2 * CSTRIDE);
        f4 R3 = __builtin_nontemporal_load(r4 + 3 * CSTRIDE);
        f4 A3 = __builtin_nontemporal_load(a4 + 3 * CSTRIDE);
        // compile-time fence: no instruction crosses -> all 8 loads issue
        // before any consumer; waitcnt becomes counted, not vmcnt(0)-pairs.
        __builtin_amdgcn_sched_barrier(0);
        f4 d;
        d = R0 - A0; acc += d * d;   // ext_vector elementwise fma
        d = R1 - A1; acc += d * d;
        d = R2 - A2; acc += d * d;
        d = R3 - A3; acc += d * d;
    }

    const float scale = 1.0f / (float)Cd;   // channel mean
    atomicAdd(&binS[m.x], acc.x * scale);   // LDS atomics (5 addrs, per-block)
    atomicAdd(&binS[m.y], acc.y * scale);
    atomicAdd(&binS[m.z], acc.z * scale);
    atomicAdd(&binS[m.w], acc.w * scale);
    if (blockIdx.z == 0) {
        atomicAdd(&binC[m.x], 1.0f);
        atomicAdd(&binC[m.y], 1.0f);
        atomicAdd(&binC[m.z], 1.0f);
        atomicAdd(&binC[m.w], 1.0f);
    }
    __syncthreads();
    // one global atomic per (block,class) into the 80 final bins
    if (tid < NCLS) {
        atomicAdd(&segsum[b * NCLS + tid], binS[tid]);
        if (blockIdx.z == 0) atomicAdd(&segcnt[b * NCLS + tid], binC[tid]);
    }
}

// Kernel 2: 80 segments -> scalar. One block of 128 threads.
__global__ __launch_bounds__(128) void finalize_kernel(
    const float* __restrict__ segsum, const float* __restrict__ segcnt,
    float* __restrict__ out)
{
    __shared__ float sMax[128];
    __shared__ float sSum[128];
    const int t = threadIdx.x;

    float s = 0.0f, cnt = 0.0f;
    if (t < Bd * NCLS) { s = segsum[t]; cnt = segcnt[t]; }
    const float avg = s / fmaxf(cnt, 1.0f);   // empty segments -> 0

    sMax[t] = avg;
    __syncthreads();
#pragma unroll
    for (int off = 64; off > 0; off >>= 1) {
        if (t < off) sMax[t] = fmaxf(sMax[t], sMax[t + off]);
        __syncthreads();
    }
    const float wmax = sMax[0];

    float w = (wmax > 0.0f) ? (avg / (wmax + EPS2)) : (avg + EPS2);
    w = fminf(fmaxf(w, 0.0f), 1.0f);

    sSum[t] = s * (w * BETA + 1.0f);
    __syncthreads();
#pragma unroll
    for (int off = 64; off > 0; off >>= 1) {
        if (t < off) sSum[t] += sSum[t + off];
        __syncthreads();
    }
    if (t == 0) out[0] = sSum[0] / (float)(Bd * HWd);
}

extern "C" void kernel_launch(void* const* d_in, const int* in_sizes, int n_in,
                              void* d_out, int out_size, void* d_ws, size_t ws_size,
                              hipStream_t stream) {
    const float* rec  = (const float*)d_in[0];
    const float* aln  = (const float*)d_in[1];
    const int*   mask = (const int*)d_in[2];
    float* out = (float*)d_out;

    float* segsum = (float*)d_ws;
    float* segcnt = segsum + Bd * NCLS;

    // zero the 2*80 accumulators (ws is re-poisoned to 0xAA before every launch)
    (void)hipMemsetAsync(d_ws, 0, 2 * Bd * NCLS * sizeof(float), stream);

    dim3 grid(HWd / PIX_PER_BLOCK, Bd, NCCHUNK);   // (4, 16, 64) = 4096 blocks
    seg_partial_kernel<<<grid, 256, 0, stream>>>(rec, aln, mask, segsum, segcnt);
    finalize_kernel<<<1, 128, 0, stream>>>(segsum, segcnt, out);
}